// Round 2
// baseline (487.894 us; speedup 1.0000x reference)
//
#include <hip/hip_runtime.h>
#include <stdint.h>

// Problem constants (fixed by reference setup_inputs)
#define D_DIM 4096      // hidden dim (K)
#define E_NUM 64        // experts (N)
#define T_TOK 16384     // tokens (M) = 4*4096
#define CAPF 256.0f     // expert_capacity = int(16384/64*1.0)

using bf16x8 = __attribute__((ext_vector_type(8))) short;
using f32x4  = __attribute__((ext_vector_type(4))) float;
typedef unsigned short u16;
typedef unsigned int u32;

// Truncation split: x == hi + lo exactly (hi = x with low 16 mantissa bits zeroed,
// lo = exact residual, then lo truncated to bf16 -> error <= 2^-17 |x|).
__device__ __forceinline__ void cvt8(const float4 a, const float4 b, bf16x8& h, bf16x8& l) {
  float f[8] = {a.x, a.y, a.z, a.w, b.x, b.y, b.z, b.w};
#pragma unroll
  for (int i = 0; i < 8; ++i) {
    u32 u = __float_as_uint(f[i]);
    float lo = f[i] - __uint_as_float(u & 0xFFFF0000u);
    h[i] = (short)(u >> 16);
    l[i] = (short)(__float_as_uint(lo) >> 16);
  }
}

// Kernel 0: W (4096x64, [k][e]) -> Wh/Wl bf16 [e][k] (truncation split).
// Grid 128 blocks: block -> (expert e = bx>>1, K-half). Thread handles 8 k's,
// writes one coalesced uint4 per array.
__global__ __launch_bounds__(256) void prep_kernel(const float* __restrict__ W,
                                                   u16* __restrict__ Wh, u16* __restrict__ Wl) {
  const int e = blockIdx.x >> 1;
  const int k0 = (blockIdx.x & 1) * 2048 + threadIdx.x * 8;
  u32 hp[4], lp[4];
#pragma unroll
  for (int j = 0; j < 4; ++j) {
    u32 hh[2], ll[2];
#pragma unroll
    for (int q = 0; q < 2; ++q) {
      float w = W[(size_t)(k0 + 2 * j + q) * E_NUM + e];
      u32 u = __float_as_uint(w);
      float lo = w - __uint_as_float(u & 0xFFFF0000u);
      hh[q] = u >> 16;
      ll[q] = __float_as_uint(lo) >> 16;
    }
    hp[j] = hh[0] | (hh[1] << 16);
    lp[j] = ll[0] | (ll[1] << 16);
  }
  *(uint4*)(Wh + (size_t)e * D_DIM + k0) = make_uint4(hp[0], hp[1], hp[2], hp[3]);
  *(uint4*)(Wl + (size_t)e * D_DIM + k0) = make_uint4(lp[0], lp[1], lp[2], lp[3]);
}

// Kernel 1: barrier-free router GEMM + softmax + top-1.
// Block: 256 thr = 4 waves = 16 tokens x 4 K-quarters. Each wave: 16 tokens x 64
// experts (4 MFMA tiles) over K/4, A loaded straight from global in MFMA layout
// (no LDS staging, no inner-loop barriers). Partials combined via LDS once.
__global__ __launch_bounds__(256, 4) void gemm_softmax(
    const float* __restrict__ x, const u16* __restrict__ Wh, const u16* __restrict__ Wl,
    const float* __restrict__ bias, float* __restrict__ out,
    float* __restrict__ S, float* __restrict__ P,
    float* __restrict__ top_p, int* __restrict__ top_i) {
  __shared__ float slab[4][16][65];   // +1 pad: conflict-free row writes

  const int tid = threadIdx.x;
  const int lane = tid & 63;
  const int w = tid >> 6;        // K-quarter
  const int m = lane & 15;       // token row / expert-within-tile
  const int g = lane >> 4;       // k-octet
  const int tok_base = blockIdx.x * 16;

  const float* ap = x + (size_t)(tok_base + m) * D_DIM + w * 1024 + g * 8;
  const size_t boff = (size_t)m * D_DIM + w * 1024 + g * 8;
  const u16* bhp = Wh + boff;
  const u16* blp = Wl + boff;

  f32x4 acc[4];
#pragma unroll
  for (int t = 0; t < 4; ++t) acc[t] = (f32x4){0.f, 0.f, 0.f, 0.f};

  // Software pipeline: A distance 2 (HBM ~900cy), B-hi distance 1 (L2), B-lo distance 0.
  float4 a_pend[2][2];
  bf16x8 bh_pend[4];
  a_pend[0][0] = *(const float4*)(ap);
  a_pend[0][1] = *(const float4*)(ap + 4);
  a_pend[1][0] = *(const float4*)(ap + 32);
  a_pend[1][1] = *(const float4*)(ap + 36);
#pragma unroll
  for (int t = 0; t < 4; ++t) bh_pend[t] = *(const bf16x8*)(bhp + (size_t)t * 16 * D_DIM);

#pragma unroll 4
  for (int s = 0; s < 32; ++s) {
    const int cs = s & 1;
    float4 ca0 = a_pend[cs][0], ca1 = a_pend[cs][1];
    bf16x8 cbh[4];
#pragma unroll
    for (int t = 0; t < 4; ++t) cbh[t] = bh_pend[t];
    // B-lo for current step (consumed by the last MFMA group -> latency hidden)
    bf16x8 cbl[4];
#pragma unroll
    for (int t = 0; t < 4; ++t) cbl[t] = *(const bf16x8*)(blp + (size_t)t * 16 * D_DIM + s * 32);
    // prefetch next B-hi
    const int s1 = (s + 1 < 32) ? s + 1 : 31;   // clamp: stays in-bounds, result unused
#pragma unroll
    for (int t = 0; t < 4; ++t) bh_pend[t] = *(const bf16x8*)(bhp + (size_t)t * 16 * D_DIM + s1 * 32);
    // prefetch A two steps ahead
    const int s2 = (s + 2 < 32) ? s + 2 : 31;
    a_pend[cs][0] = *(const float4*)(ap + s2 * 32);
    a_pend[cs][1] = *(const float4*)(ap + s2 * 32 + 4);

    bf16x8 ah, al;
    cvt8(ca0, ca1, ah, al);
#pragma unroll
    for (int t = 0; t < 4; ++t) acc[t] = __builtin_amdgcn_mfma_f32_16x16x32_bf16(ah, cbh[t], acc[t], 0, 0, 0);
#pragma unroll
    for (int t = 0; t < 4; ++t) acc[t] = __builtin_amdgcn_mfma_f32_16x16x32_bf16(al, cbh[t], acc[t], 0, 0, 0);
#pragma unroll
    for (int t = 0; t < 4; ++t) acc[t] = __builtin_amdgcn_mfma_f32_16x16x32_bf16(ah, cbl[t], acc[t], 0, 0, 0);
  }

  // ---- combine K-quarters + epilogue ----
  // C/D layout: col = lane&15 (expert-in-tile), row = g*4 + r.
#pragma unroll
  for (int t = 0; t < 4; ++t)
#pragma unroll
    for (int r = 0; r < 4; ++r)
      slab[w][g * 4 + r][t * 16 + m] = acc[t][r];
  __syncthreads();

  const int j = tid >> 4;   // token 0..15 (wave-aligned 16-lane groups)
  const int c0 = tid & 15;
  float v[4];
#pragma unroll
  for (int i = 0; i < 4; ++i) {
    const int e = c0 + 16 * i;
    v[i] = bias[e] + slab[0][j][e] + slab[1][j][e] + slab[2][j][e] + slab[3][j][e];
  }

  float best = v[0]; int bi = c0;
#pragma unroll
  for (int i = 1; i < 4; ++i)
    if (v[i] > best) { best = v[i]; bi = c0 + 16 * i; }
#pragma unroll
  for (int d = 1; d <= 8; d <<= 1) {   // reduce across the 16-lane token group
    float ob = __shfl_xor(best, d);
    int oi = __shfl_xor(bi, d);
    if (ob > best || (ob == best && oi < bi)) { best = ob; bi = oi; }
  }
  float ex[4], ssum = 0.f;
#pragma unroll
  for (int i = 0; i < 4; ++i) { ex[i] = __expf(v[i] - best); ssum += ex[i]; }
#pragma unroll
  for (int d = 1; d <= 8; d <<= 1) ssum += __shfl_xor(ssum, d);

  const int gt = tok_base + j;
#pragma unroll
  for (int i = 0; i < 4; ++i) {
    float p = ex[i] / ssum;
    out[(size_t)gt * 64 + c0 + 16 * i] = p;
    slab[0][j][c0 + 16 * i] = p;    // each (j,e) slot written by its own reader-thread
  }
  if (c0 == 0) {
    float tp = 1.0f / ssum;          // top prob: exp(best-best)/ssum
    top_p[gt] = tp;
    top_i[gt] = bi;
    atomicAdd(&S[bi], tp);
  }
  __syncthreads();
  if (tid < 64) {                    // per-expert prob sums over 16 tokens
    float sacc = 0.f;
#pragma unroll
    for (int jj = 0; jj < 16; ++jj) sacc += slab[0][jj][tid];
    atomicAdd(&P[tid], sacc);
  }
}

// Kernel 2: aux loss scalar
__global__ __launch_bounds__(64) void aux_kernel(float* __restrict__ out,
                                                 const float* __restrict__ S,
                                                 const float* __restrict__ P) {
  int l = threadIdx.x;
  float v = S[l] * P[l];
#pragma unroll
  for (int d = 1; d <= 32; d <<= 1) v += __shfl_xor(v, d);
  if (l == 0) out[(size_t)T_TOK * E_NUM] = 0.01f * 64.0f * v / ((float)T_TOK * (float)T_TOK);
}

// Kernel 3: capacity masking. Fast path: expert top-prob sum <= 256 -> all tokens kept
// (cumsum monotone, probs > 0). Exact O(T) scan only if an expert overflows.
__global__ __launch_bounds__(256) void finalize_kernel(float* __restrict__ out,
                                                       const float* __restrict__ top_p,
                                                       const int* __restrict__ top_i,
                                                       const float* __restrict__ S) {
  int t = blockIdx.x * 256 + threadIdx.x;
  int e = top_i[t];
  float se = S[e];
  if (se > CAPF) {
    float p = top_p[t];
    float G = 0.f;
    for (int u = 0; u < T_TOK; ++u) {
      if (top_i[u] == e) {
        float q = top_p[u];
        if (q > p || (q == p && u <= t)) G += q;
      }
    }
    if (G > CAPF) {
      float4 z = {0.f, 0.f, 0.f, 0.f};
      float4* row = (float4*)(out + (size_t)t * 64);
#pragma unroll
      for (int i = 0; i < 16; ++i) row[i] = z;
    }
  }
}

extern "C" void kernel_launch(void* const* d_in, const int* in_sizes, int n_in,
                              void* d_out, int out_size, void* d_ws, size_t ws_size,
                              hipStream_t stream) {
  const float* x = (const float*)d_in[0];
  const float* W = (const float*)d_in[1];
  const float* b = (const float*)d_in[2];
  float* out = (float*)d_out;

  // ws layout (~1.2 MB)
  u16* Wh = (u16*)d_ws;
  u16* Wl = Wh + (size_t)E_NUM * D_DIM;
  float* S = (float*)(Wl + (size_t)E_NUM * D_DIM);
  float* P = S + 64;
  float* top_p = P + 64;
  int* top_i = (int*)(top_p + T_TOK);

  hipMemsetAsync(S, 0, 2 * 64 * sizeof(float), stream);
  prep_kernel<<<128, 256, 0, stream>>>(W, Wh, Wl);
  gemm_softmax<<<T_TOK / 16, 256, 0, stream>>>(x, Wh, Wl, b, out, S, P, top_p, top_i);
  aux_kernel<<<1, 64, 0, stream>>>(out, S, P);
  finalize_kernel<<<T_TOK / 256, 256, 0, stream>>>(out, top_p, top_i, S);
}

// Round 3
// 427.584 us; speedup vs baseline: 1.1410x; 1.1410x over previous
//
#include <hip/hip_runtime.h>
#include <stdint.h>

// Problem constants (fixed by reference setup_inputs)
#define D_DIM 4096      // hidden dim (K)
#define E_NUM 64        // experts (N)
#define T_TOK 16384     // tokens (M) = 4*4096
#define CAPF 256.0f     // expert_capacity = int(16384/64*1.0)
#define NSTEP 16        // K steps of BK=256 floats
#define ROWS 32         // tokens per block

using bf16x8 = __attribute__((ext_vector_type(8))) short;
using f32x4  = __attribute__((ext_vector_type(4))) float;
typedef unsigned short u16;
typedef unsigned int u32;

// Async global->LDS DMA, 16B per lane. LDS dest = wave-uniform base + lane*16.
__device__ __forceinline__ void dma16(const float* g, float* l) {
  __builtin_amdgcn_global_load_lds(
      (const __attribute__((address_space(1))) void*)g,
      (__attribute__((address_space(3))) void*)l, 16, 0, 0);
}

// Truncation split: x == hi + lo exactly; lo then truncated to bf16 (err <= 2^-17 |x|).
__device__ __forceinline__ void cvt8(const float4 a, const float4 b, bf16x8& h, bf16x8& l) {
  float f[8] = {a.x, a.y, a.z, a.w, b.x, b.y, b.z, b.w};
#pragma unroll
  for (int i = 0; i < 8; ++i) {
    u32 u = __float_as_uint(f[i]);
    float lo = f[i] - __uint_as_float(u & 0xFFFF0000u);
    h[i] = (short)(u >> 16);
    l[i] = (short)(__float_as_uint(lo) >> 16);
  }
}

// Kernel 0: W (4096x64, [k][e]) -> Wh/Wl bf16 [e][k] (truncation split).
__global__ __launch_bounds__(256) void prep_kernel(const float* __restrict__ W,
                                                   u16* __restrict__ Wh, u16* __restrict__ Wl) {
  const int e = blockIdx.x >> 1;
  const int k0 = (blockIdx.x & 1) * 2048 + threadIdx.x * 8;
  u32 hp[4], lp[4];
#pragma unroll
  for (int j = 0; j < 4; ++j) {
    u32 hh[2], ll[2];
#pragma unroll
    for (int q = 0; q < 2; ++q) {
      float w = W[(size_t)(k0 + 2 * j + q) * E_NUM + e];
      u32 u = __float_as_uint(w);
      float lo = w - __uint_as_float(u & 0xFFFF0000u);
      hh[q] = u >> 16;
      ll[q] = __float_as_uint(lo) >> 16;
    }
    hp[j] = hh[0] | (hh[1] << 16);
    lp[j] = ll[0] | (ll[1] << 16);
  }
  *(uint4*)(Wh + (size_t)e * D_DIM + k0) = make_uint4(hp[0], hp[1], hp[2], hp[3]);
  *(uint4*)(Wl + (size_t)e * D_DIM + k0) = make_uint4(lp[0], lp[1], lp[2], lp[3]);
}

// Kernel 1: m97-style DMA-staged router GEMM + softmax + top-1.
// Block: 256 thr = 4 waves, 32 tokens. Wave kh: 32 tokens x 64 experts over
// K-quarter [kh*64, kh*64+64) of each staged BK=256 chunk. x staged to LDS via
// global_load_lds (dbuf, 64KB total). One barrier per step. K-partials combined
// via LDS slab, then softmax/top-1 epilogue.
__global__ __launch_bounds__(256, 2) void gemm_softmax(
    const float* __restrict__ x, const u16* __restrict__ Wh, const u16* __restrict__ Wl,
    const float* __restrict__ bias, float* __restrict__ out,
    float* __restrict__ S, float* __restrict__ P,
    float* __restrict__ top_p, int* __restrict__ top_i) {
  __shared__ float smem[16384];   // 64KB: 2 x (32 rows x 256 floats); reused as slab

  const int tid = threadIdx.x;
  const int lane = tid & 63;
  const int kh = tid >> 6;       // K-quarter (wave id)
  const int m = lane & 15;       // token-in-tile (A row) / expert-in-tile (B row)
  const int g = lane >> 4;       // k-octet
  const int tok_base = blockIdx.x * ROWS;

  f32x4 acc[2][4];               // [row-tile][col-tile]
#pragma unroll
  for (int rt = 0; rt < 2; ++rt)
#pragma unroll
    for (int ct = 0; ct < 4; ++ct) acc[rt][ct] = (f32x4){0.f, 0.f, 0.f, 0.f};

  // prologue: stage step 0 into buffer 0 (wave kh stages rows [8kh, 8kh+8))
#pragma unroll
  for (int i = 0; i < 8; ++i) {
    const int r = kh * 8 + i;
    dma16(x + (size_t)(tok_base + r) * D_DIM + lane * 4, smem + r * 256);
  }

  for (int s = 0; s < NSTEP; ++s) {
    __syncthreads();             // drains DMA(s) (issued a full step ago) + syncs buffers
    const int buf = s & 1;
    const float* Ab = smem + buf * 8192;

    // (1) B fragments for both K32 sub-steps (L2/L1-resident Wt)
    bf16x8 bh[2][4], bl[2][4];
#pragma unroll
    for (int j = 0; j < 2; ++j) {
      const int kg = s * 256 + kh * 64 + j * 32 + g * 8;
#pragma unroll
      for (int ct = 0; ct < 4; ++ct) {
        const size_t o = (size_t)(ct * 16 + m) * D_DIM + kg;
        bh[j][ct] = *(const bf16x8*)(Wh + o);
        bl[j][ct] = *(const bf16x8*)(Wl + o);
      }
    }
    // (2) A fp32 fragments from LDS
    float4 af[2][2][2];
#pragma unroll
    for (int j = 0; j < 2; ++j)
#pragma unroll
      for (int rt = 0; rt < 2; ++rt) {
        const float* ap = Ab + (rt * 16 + m) * 256 + kh * 64 + j * 32 + g * 8;
        af[j][rt][0] = *(const float4*)ap;
        af[j][rt][1] = *(const float4*)(ap + 4);
      }
    // (3) issue DMA for step s+1 (younger than B loads -> B's vmcnt(N) won't drain it)
    if (s + 1 < NSTEP) {
#pragma unroll
      for (int i = 0; i < 8; ++i) {
        const int r = kh * 8 + i;
        dma16(x + (size_t)(tok_base + r) * D_DIM + (s + 1) * 256 + lane * 4,
              smem + (buf ^ 1) * 8192 + r * 256);
      }
    }
    // (4) convert + (5) MFMA
    bf16x8 ah[2][2], al[2][2];
#pragma unroll
    for (int j = 0; j < 2; ++j)
#pragma unroll
      for (int rt = 0; rt < 2; ++rt) cvt8(af[j][rt][0], af[j][rt][1], ah[j][rt], al[j][rt]);
#pragma unroll
    for (int j = 0; j < 2; ++j)
#pragma unroll
      for (int rt = 0; rt < 2; ++rt)
#pragma unroll
        for (int ct = 0; ct < 4; ++ct) {
          acc[rt][ct] = __builtin_amdgcn_mfma_f32_16x16x32_bf16(ah[j][rt], bh[j][ct], acc[rt][ct], 0, 0, 0);
          acc[rt][ct] = __builtin_amdgcn_mfma_f32_16x16x32_bf16(al[j][rt], bh[j][ct], acc[rt][ct], 0, 0, 0);
          acc[rt][ct] = __builtin_amdgcn_mfma_f32_16x16x32_bf16(ah[j][rt], bl[j][ct], acc[rt][ct], 0, 0, 0);
        }
  }

  // ---- combine K-quarters: slab[4][32][66] aliased onto smem ----
  __syncthreads();   // all waves done reading LDS buffers
  // C/D layout: token-in-tile = g*4+r, expert-in-tile = m (verified rounds 1-2)
#pragma unroll
  for (int rt = 0; rt < 2; ++rt)
#pragma unroll
    for (int ct = 0; ct < 4; ++ct)
#pragma unroll
      for (int r = 0; r < 4; ++r)
        smem[kh * 2112 + (rt * 16 + g * 4 + r) * 66 + ct * 16 + m] = acc[rt][ct][r];
  __syncthreads();

  // softmax: 8 threads per token, 8 experts each
  const int j = tid >> 3;
  const int q = tid & 7;
  float v[8];
#pragma unroll
  for (int i = 0; i < 8; ++i) {
    const int e = q * 8 + i;
    v[i] = bias[e] + smem[j * 66 + e] + smem[2112 + j * 66 + e]
                   + smem[4224 + j * 66 + e] + smem[6336 + j * 66 + e];
  }
  float best = v[0]; int bi = q * 8;
#pragma unroll
  for (int i = 1; i < 8; ++i)
    if (v[i] > best) { best = v[i]; bi = q * 8 + i; }
#pragma unroll
  for (int d = 1; d <= 4; d <<= 1) {   // reduce across the 8-lane token group
    float ob = __shfl_xor(best, d);
    int oi = __shfl_xor(bi, d);
    if (ob > best || (ob == best && oi < bi)) { best = ob; bi = oi; }
  }
  float ex[8], ssum = 0.f;
#pragma unroll
  for (int i = 0; i < 8; ++i) { ex[i] = __expf(v[i] - best); ssum += ex[i]; }
#pragma unroll
  for (int d = 1; d <= 4; d <<= 1) ssum += __shfl_xor(ssum, d);
  const float rs = 1.0f / ssum;

  const int gt = tok_base + j;
#pragma unroll
  for (int i = 0; i < 8; ++i) {
    float p = ex[i] * rs;
    out[(size_t)gt * 64 + q * 8 + i] = p;
    smem[j * 66 + q * 8 + i] = p;     // own slots only (safe without barrier)
  }
  if (q == 0) {
    top_p[gt] = rs;                    // top prob = exp(best-best)/ssum
    top_i[gt] = bi;
    atomicAdd(&S[bi], rs);
  }
  __syncthreads();
  if (tid < 64) {                      // per-expert prob sums over 32 tokens
    float sa = 0.f;
#pragma unroll
    for (int jj = 0; jj < ROWS; ++jj) sa += smem[jj * 66 + tid];
    atomicAdd(&P[tid], sa);
  }
}

// Kernel 2: aux loss scalar
__global__ __launch_bounds__(64) void aux_kernel(float* __restrict__ out,
                                                 const float* __restrict__ S,
                                                 const float* __restrict__ P) {
  int l = threadIdx.x;
  float v = S[l] * P[l];
#pragma unroll
  for (int d = 1; d <= 32; d <<= 1) v += __shfl_xor(v, d);
  if (l == 0) out[(size_t)T_TOK * E_NUM] = 0.01f * 64.0f * v / ((float)T_TOK * (float)T_TOK);
}

// Kernel 3: capacity masking. Fast path: expert top-prob sum <= 256 -> all tokens kept
// (cumsum monotone, probs > 0). Exact O(T) scan only if an expert overflows.
__global__ __launch_bounds__(256) void finalize_kernel(float* __restrict__ out,
                                                       const float* __restrict__ top_p,
                                                       const int* __restrict__ top_i,
                                                       const float* __restrict__ S) {
  int t = blockIdx.x * 256 + threadIdx.x;
  int e = top_i[t];
  float se = S[e];
  if (se > CAPF) {
    float p = top_p[t];
    float G = 0.f;
    for (int u = 0; u < T_TOK; ++u) {
      if (top_i[u] == e) {
        float q = top_p[u];
        if (q > p || (q == p && u <= t)) G += q;
      }
    }
    if (G > CAPF) {
      float4 z = {0.f, 0.f, 0.f, 0.f};
      float4* row = (float4*)(out + (size_t)t * 64);
#pragma unroll
      for (int i = 0; i < 16; ++i) row[i] = z;
    }
  }
}

extern "C" void kernel_launch(void* const* d_in, const int* in_sizes, int n_in,
                              void* d_out, int out_size, void* d_ws, size_t ws_size,
                              hipStream_t stream) {
  const float* x = (const float*)d_in[0];
  const float* W = (const float*)d_in[1];
  const float* b = (const float*)d_in[2];
  float* out = (float*)d_out;

  // ws layout (~1.2 MB)
  u16* Wh = (u16*)d_ws;
  u16* Wl = Wh + (size_t)E_NUM * D_DIM;
  float* S = (float*)(Wl + (size_t)E_NUM * D_DIM);
  float* P = S + 64;
  float* top_p = P + 64;
  int* top_i = (int*)(top_p + T_TOK);

  hipMemsetAsync(S, 0, 2 * 64 * sizeof(float), stream);
  prep_kernel<<<128, 256, 0, stream>>>(W, Wh, Wl);
  gemm_softmax<<<T_TOK / ROWS, 256, 0, stream>>>(x, Wh, Wl, b, out, S, P, top_p, top_i);
  aux_kernel<<<1, 64, 0, stream>>>(out, S, P);
  finalize_kernel<<<T_TOK / 256, 256, 0, stream>>>(out, top_p, top_i, S);
}

// Round 4
// 424.902 us; speedup vs baseline: 1.1482x; 1.0063x over previous
//
#include <hip/hip_runtime.h>
#include <stdint.h>

// Problem constants (fixed by reference setup_inputs)
#define D_DIM 4096      // hidden dim (K)
#define E_NUM 64        // experts (N)
#define T_TOK 16384     // tokens (M) = 4*4096
#define CAPF 256.0f     // expert_capacity = int(16384/64*1.0)
#define NSTEP 16        // K steps of BK=256 floats
#define ROWS 32         // tokens per block
#define LDA 260         // padded LDS row stride (floats); 1040B, 16B-aligned, breaks 16-way conflicts
#define BUFSZ (ROWS * LDA)   // 8320 floats per stage buffer

using bf16x8 = __attribute__((ext_vector_type(8))) short;
using f32x4  = __attribute__((ext_vector_type(4))) float;
typedef unsigned short u16;
typedef unsigned int u32;

// Async global->LDS DMA, 16B per lane. LDS dest = wave-uniform base + lane*16.
__device__ __forceinline__ void dma16(const float* g, float* l) {
  __builtin_amdgcn_global_load_lds(
      (const __attribute__((address_space(1))) void*)g,
      (__attribute__((address_space(3))) void*)l, 16, 0, 0);
}

// Truncation split: x == hi + lo exactly; lo then truncated to bf16 (err <= 2^-17 |x|).
__device__ __forceinline__ void cvt8(const float4 a, const float4 b, bf16x8& h, bf16x8& l) {
  float f[8] = {a.x, a.y, a.z, a.w, b.x, b.y, b.z, b.w};
#pragma unroll
  for (int i = 0; i < 8; ++i) {
    u32 u = __float_as_uint(f[i]);
    float lo = f[i] - __uint_as_float(u & 0xFFFF0000u);
    h[i] = (short)(u >> 16);
    l[i] = (short)(__float_as_uint(lo) >> 16);
  }
}

// Kernel 0: W (4096x64, [k][e]) -> Wp/Wlp packed in MFMA B-fragment order:
//   Wp[((kk*4 + ct)*64 + lane)*8 + i] = hi(W[kk*32 + (lane>>4)*8 + i][ct*16 + (lane&15)])
// so the GEMM's B-load is base + lane*16 (fully coalesced), no gathers.
__global__ __launch_bounds__(256) void prep_kernel(const float* __restrict__ W,
                                                   u16* __restrict__ Wp, u16* __restrict__ Wlp) {
  const int t = blockIdx.x * 256 + threadIdx.x;   // 32768 threads, one 16B chunk each
  const int lane = t & 63;
  const int ct = (t >> 6) & 3;
  const int kk = t >> 8;
  const int e = ct * 16 + (lane & 15);
  const int k0 = kk * 32 + (lane >> 4) * 8;
  u32 hp[4], lp[4];
#pragma unroll
  for (int j = 0; j < 4; ++j) {
    u32 hh[2], ll[2];
#pragma unroll
    for (int q = 0; q < 2; ++q) {
      float w = W[(size_t)(k0 + 2 * j + q) * E_NUM + e];
      u32 u = __float_as_uint(w);
      float lo = w - __uint_as_float(u & 0xFFFF0000u);
      hh[q] = u >> 16;
      ll[q] = __float_as_uint(lo) >> 16;
    }
    hp[j] = hh[0] | (hh[1] << 16);
    lp[j] = ll[0] | (ll[1] << 16);
  }
  *(uint4*)(Wp  + (size_t)t * 8) = make_uint4(hp[0], hp[1], hp[2], hp[3]);
  *(uint4*)(Wlp + (size_t)t * 8) = make_uint4(lp[0], lp[1], lp[2], lp[3]);
}

// Kernel 1: DMA-staged router GEMM + softmax + top-1.
// Block: 256 thr = 4 waves, 32 tokens. Wave kh: 32 tokens x 64 experts over
// K-quarter [kh*64, kh*64+64) of each staged BK=256 chunk. x staged to LDS via
// global_load_lds (dbuf, padded rows). B read as pre-packed coalesced fragments.
// Issue order per step: B (coalesced) -> A ds_reads -> DMA(s+1) -> cvt -> MFMA,
// so the B-wait is vmcnt(8) and never drains the younger DMAs.
__global__ __launch_bounds__(256, 2) void gemm_softmax(
    const float* __restrict__ x, const u16* __restrict__ Wp, const u16* __restrict__ Wlp,
    const float* __restrict__ bias, float* __restrict__ out,
    float* __restrict__ S, float* __restrict__ P,
    float* __restrict__ top_p, int* __restrict__ top_i) {
  __shared__ float smem[2 * BUFSZ];   // 66560 B; reused as epilogue slab

  const int tid = threadIdx.x;
  const int lane = tid & 63;
  const int kh = tid >> 6;       // K-quarter (wave id)
  const int m = lane & 15;       // token-in-tile (A row)
  const int g = lane >> 4;       // k-octet
  const int tok_base = blockIdx.x * ROWS;

  f32x4 acc[2][4];               // [row-tile][col-tile]
#pragma unroll
  for (int rt = 0; rt < 2; ++rt)
#pragma unroll
    for (int ct = 0; ct < 4; ++ct) acc[rt][ct] = (f32x4){0.f, 0.f, 0.f, 0.f};

  // prologue: stage step 0 into buffer 0 (wave kh stages rows [8kh, 8kh+8))
#pragma unroll
  for (int i = 0; i < 8; ++i) {
    const int r = kh * 8 + i;
    dma16(x + (size_t)(tok_base + r) * D_DIM + lane * 4, smem + r * LDA);
  }

  for (int s = 0; s < NSTEP; ++s) {
    __syncthreads();             // drains DMA(s) (in flight a full step) + buffer handoff
    const int buf = s & 1;
    const float* Ab = smem + buf * BUFSZ;

    // (1) B fragments, packed-coalesced: 16 x 1KB contiguous wave-loads from L1/L2
    bf16x8 bh[2][4], bl[2][4];
#pragma unroll
    for (int j = 0; j < 2; ++j) {
      const int kk = s * 8 + kh * 2 + j;        // k32-chunk index
#pragma unroll
      for (int ct = 0; ct < 4; ++ct) {
        const size_t o = ((size_t)(kk * 4 + ct) * 64 + lane) * 8;
        bh[j][ct] = *(const bf16x8*)(Wp + o);
        bl[j][ct] = *(const bf16x8*)(Wlp + o);
      }
    }
    // (2) A fp32 fragments from LDS (lgkmcnt — independent of vmem counter)
    float4 af[2][2][2];
#pragma unroll
    for (int j = 0; j < 2; ++j)
#pragma unroll
      for (int rt = 0; rt < 2; ++rt) {
        const float* ap = Ab + (rt * 16 + m) * LDA + kh * 64 + j * 32 + g * 8;
        af[j][rt][0] = *(const float4*)ap;
        af[j][rt][1] = *(const float4*)(ap + 4);
      }
    // (3) issue DMA for step s+1 (younger than B loads -> B's vmcnt(8) won't drain it)
    if (s + 1 < NSTEP) {
#pragma unroll
      for (int i = 0; i < 8; ++i) {
        const int r = kh * 8 + i;
        dma16(x + (size_t)(tok_base + r) * D_DIM + (s + 1) * 256 + lane * 4,
              smem + (buf ^ 1) * BUFSZ + r * LDA);
      }
    }
    // (4) convert + (5) MFMA
    bf16x8 ah[2][2], al[2][2];
#pragma unroll
    for (int j = 0; j < 2; ++j)
#pragma unroll
      for (int rt = 0; rt < 2; ++rt) cvt8(af[j][rt][0], af[j][rt][1], ah[j][rt], al[j][rt]);
#pragma unroll
    for (int j = 0; j < 2; ++j)
#pragma unroll
      for (int rt = 0; rt < 2; ++rt)
#pragma unroll
        for (int ct = 0; ct < 4; ++ct) {
          acc[rt][ct] = __builtin_amdgcn_mfma_f32_16x16x32_bf16(ah[j][rt], bh[j][ct], acc[rt][ct], 0, 0, 0);
          acc[rt][ct] = __builtin_amdgcn_mfma_f32_16x16x32_bf16(al[j][rt], bh[j][ct], acc[rt][ct], 0, 0, 0);
          acc[rt][ct] = __builtin_amdgcn_mfma_f32_16x16x32_bf16(ah[j][rt], bl[j][ct], acc[rt][ct], 0, 0, 0);
        }
  }

  // ---- combine K-quarters: slab[4][32][66] aliased onto smem ----
  __syncthreads();   // all waves done reading LDS buffers
  // C/D layout: token-in-tile = g*4+r, expert-in-tile = m (verified rounds 1-3)
#pragma unroll
  for (int rt = 0; rt < 2; ++rt)
#pragma unroll
    for (int ct = 0; ct < 4; ++ct)
#pragma unroll
      for (int r = 0; r < 4; ++r)
        smem[kh * 2112 + (rt * 16 + g * 4 + r) * 66 + ct * 16 + m] = acc[rt][ct][r];
  __syncthreads();

  // softmax: 8 threads per token, 8 experts each
  const int j = tid >> 3;
  const int q = tid & 7;
  float v[8];
#pragma unroll
  for (int i = 0; i < 8; ++i) {
    const int e = q * 8 + i;
    v[i] = bias[e] + smem[j * 66 + e] + smem[2112 + j * 66 + e]
                   + smem[4224 + j * 66 + e] + smem[6336 + j * 66 + e];
  }
  float best = v[0]; int bi = q * 8;
#pragma unroll
  for (int i = 1; i < 8; ++i)
    if (v[i] > best) { best = v[i]; bi = q * 8 + i; }
#pragma unroll
  for (int d = 1; d <= 4; d <<= 1) {   // reduce across the 8-lane token group
    float ob = __shfl_xor(best, d);
    int oi = __shfl_xor(bi, d);
    if (ob > best || (ob == best && oi < bi)) { best = ob; bi = oi; }
  }
  float ex[8], ssum = 0.f;
#pragma unroll
  for (int i = 0; i < 8; ++i) { ex[i] = __expf(v[i] - best); ssum += ex[i]; }
#pragma unroll
  for (int d = 1; d <= 4; d <<= 1) ssum += __shfl_xor(ssum, d);
  const float rs = 1.0f / ssum;

  const int gt = tok_base + j;
#pragma unroll
  for (int i = 0; i < 8; ++i) {
    float p = ex[i] * rs;
    out[(size_t)gt * 64 + q * 8 + i] = p;
    smem[j * 66 + q * 8 + i] = p;     // own slots only (safe without barrier)
  }
  if (q == 0) {
    top_p[gt] = rs;                    // top prob = exp(best-best)/ssum
    top_i[gt] = bi;
    atomicAdd(&S[bi], rs);
  }
  __syncthreads();
  if (tid < 64) {                      // per-expert prob sums over 32 tokens
    float sa = 0.f;
#pragma unroll
    for (int jj = 0; jj < ROWS; ++jj) sa += smem[jj * 66 + tid];
    atomicAdd(&P[tid], sa);
  }
}

// Kernel 2: aux loss scalar
__global__ __launch_bounds__(64) void aux_kernel(float* __restrict__ out,
                                                 const float* __restrict__ S,
                                                 const float* __restrict__ P) {
  int l = threadIdx.x;
  float v = S[l] * P[l];
#pragma unroll
  for (int d = 1; d <= 32; d <<= 1) v += __shfl_xor(v, d);
  if (l == 0) out[(size_t)T_TOK * E_NUM] = 0.01f * 64.0f * v / ((float)T_TOK * (float)T_TOK);
}

// Kernel 3: capacity masking. Fast path: expert top-prob sum <= 256 -> all tokens kept
// (cumsum monotone, probs > 0). Exact O(T) scan only if an expert overflows.
__global__ __launch_bounds__(256) void finalize_kernel(float* __restrict__ out,
                                                       const float* __restrict__ top_p,
                                                       const int* __restrict__ top_i,
                                                       const float* __restrict__ S) {
  int t = blockIdx.x * 256 + threadIdx.x;
  int e = top_i[t];
  float se = S[e];
  if (se > CAPF) {
    float p = top_p[t];
    float G = 0.f;
    for (int u = 0; u < T_TOK; ++u) {
      if (top_i[u] == e) {
        float q = top_p[u];
        if (q > p || (q == p && u <= t)) G += q;
      }
    }
    if (G > CAPF) {
      float4 z = {0.f, 0.f, 0.f, 0.f};
      float4* row = (float4*)(out + (size_t)t * 64);
#pragma unroll
      for (int i = 0; i < 16; ++i) row[i] = z;
    }
  }
}

extern "C" void kernel_launch(void* const* d_in, const int* in_sizes, int n_in,
                              void* d_out, int out_size, void* d_ws, size_t ws_size,
                              hipStream_t stream) {
  const float* x = (const float*)d_in[0];
  const float* W = (const float*)d_in[1];
  const float* b = (const float*)d_in[2];
  float* out = (float*)d_out;

  // ws layout (~1.2 MB)
  u16* Wp = (u16*)d_ws;
  u16* Wlp = Wp + (size_t)E_NUM * D_DIM;
  float* S = (float*)(Wlp + (size_t)E_NUM * D_DIM);
  float* P = S + 64;
  float* top_p = P + 64;
  int* top_i = (int*)(top_p + T_TOK);

  hipMemsetAsync(S, 0, 2 * 64 * sizeof(float), stream);
  prep_kernel<<<128, 256, 0, stream>>>(W, Wp, Wlp);
  gemm_softmax<<<T_TOK / ROWS, 256, 0, stream>>>(x, Wp, Wlp, b, out, S, P, top_p, top_i);
  aux_kernel<<<1, 64, 0, stream>>>(out, S, P);
  finalize_kernel<<<T_TOK / 256, 256, 0, stream>>>(out, top_p, top_i, S);
}